// Round 8
// baseline (3933.875 us; speedup 1.0000x reference)
//
#include <hip/hip_runtime.h>
#include <hip/hip_bf16.h>

typedef __attribute__((ext_vector_type(8))) short short8;
typedef __attribute__((ext_vector_type(4))) float f32x4;
typedef unsigned long long u64;

#define V_N 10000
#define D_E 128
#define H_N 512
#define B_N 32
#define S_N 512

#define SENT64 0xFFFFFFFFFFFFFFFFull   // 4x bf16 NaN: unreachable for finite h

// ---- workspace layout (bytes) ----
#define OFF_RP    0                        // rowpart: 16384 rows x 80 slots f32 = 5,242,880
#define OFF_EMB   5242880                  // S*B*D bf16 = 4,194,304
#define OFF_HS    (OFF_EMB + 4194304)      // S*B*H bf16 = 16,777,216
#define OFF_WOUT  (OFF_HS + 16777216)      // V*H bf16 = 10,240,000

// ------------------------------------------------------------------
__device__ __forceinline__ float ftanh(float x) {
  float e = __expf(-2.f * fabsf(x));          // in (0,1], overflow-safe
  float r = (1.f - e) / (1.f + e);
  return __builtin_copysignf(r, x);
}

__device__ __forceinline__ short8 frag2(u64 lo, u64 hi) {
  union { u64 q[2]; short8 s; } u;
  u.q[0] = lo; u.q[1] = hi;
  return u.s;
}

// ------------------------------------------------------------------
// prep: embedding gather -> bf16 [s][b][d]
__global__ void k_prep_emb(const int* __restrict__ x, const float* __restrict__ tab,
                           __hip_bfloat16* __restrict__ emb) {
  int i = blockIdx.x * 256 + threadIdx.x;         // over S*B*D = 2,097,152
  if (i >= S_N * B_N * D_E) return;
  int d  = i & (D_E - 1);
  int sb = i >> 7;
  int b  = sb & (B_N - 1);
  int s  = sb >> 5;
  int tok = x[b * S_N + s];
  emb[i] = __float2bfloat16(tab[tok * D_E + d]);
}

// prep: W_out -> bf16
__global__ void k_prep_wout(const float* __restrict__ w, __hip_bfloat16* __restrict__ o) {
  int i = blockIdx.x * 256 + threadIdx.x;
  if (i < V_N * H_N) o[i] = __float2bfloat16(w[i]);
}

// ------------------------------------------------------------------
// persistent recurrence: 64 WGs, WG w owns h-elements j = 8w..8w+7.
// A (weights) in registers; K=640 split across 4 waves.
// B fragments are polled DIRECTLY into registers from hs[t-1] (write-once
// sentinel slots): lane l's MFMA B-fragment = 2 contiguous u64 of example
// (l&15 / 16+(l&15)) -> no LDS staging, no ds_read, poll == operand ready.
// Wave 0 additionally loads 8 emb fragments with plain cached 16B loads.
__launch_bounds__(256, 1)
__global__ void k_recurrence(const int* __restrict__ x,
                             const float* __restrict__ W_ih, const float* __restrict__ W_hh,
                             const float* __restrict__ b_ih, const float* __restrict__ b_hh,
                             const __hip_bfloat16* __restrict__ emb,
                             __hip_bfloat16* __restrict__ hs)     // [512][32][512]
{
  __shared__ float gl4[4][64][33];         // per-wave partial gates
  __shared__ float bias[64];
  __shared__ unsigned short hloc[8][32];   // [jj][b] bf16 bits of new h

  const int tid = threadIdx.x;
  const int wg  = blockIdx.x;              // 0..63
  const int lane = tid & 63, kw = tid >> 6;       // kw = wave = K-slice
  const int lrow = lane & 15, lk = (lane >> 4) * 8;
  const int b_ep = tid & 31, jj_ep = tid >> 5;    // epilogue mapping 32x8

  // ---- one-time: A-fragments (64 rows x K-slice 160) into registers ----
  short8 Afrag[20];                        // [mt*5+ks], 80 VGPRs
  #pragma unroll
  for (int mt = 0; mt < 4; ++mt) {
    #pragma unroll
    for (int ks = 0; ks < 5; ++ks) {
      int lr = mt * 16 + lrow;             // local gate row 0..63
      int q = lr >> 4, kc = (lr >> 3) & 1, jj = lr & 7;
      int grow = kc * 2048 + q * 512 + wg * 8 + jj;
      int c0 = kw * 160 + ks * 32 + lk;
      short8 a;
      #pragma unroll
      for (int e = 0; e < 8; ++e) {
        int c = c0 + e;
        float v = (c < 128) ? W_ih[(size_t)grow * 128 + c]
                            : W_hh[(size_t)grow * 512 + (c - 128)];
        __hip_bfloat16 hb = __float2bfloat16(v);
        a[e] = *(const short*)&hb;
      }
      Afrag[mt * 5 + ks] = a;
    }
  }
  if (tid < 64) {
    int lr = tid;
    int q = lr >> 4, kc = (lr >> 3) & 1, jj = lr & 7;
    int grow = kc * 2048 + q * 512 + wg * 8 + jj;
    bias[lr] = b_ih[grow] + b_hh[grow];
  }

  // ---- preload token parity bits into registers (b_ep's row of x) ----
  unsigned par[16];
  #pragma unroll
  for (int w = 0; w < 16; ++w) {
    unsigned p = 0;
    for (int bb = 0; bb < 32; ++bb)
      p |= (unsigned)(x[b_ep * S_N + w * 32 + bb] & 1) << bb;
    par[w] = p;
  }

  // per-lane u64 offsets within an hs[t] block (4096 u64) for the polled frags
  // waves 1..3: 20 slots (b0: f=0..4 -> ids 2f,2f+1 ; b1: f=5..9)
  // wave 0:      4 slots (ks=4 frag of b0,b1)
  int off[20];
  if (kw == 0) {
    #pragma unroll
    for (int f = 0; f < 2; ++f) {
      int ex = lrow + f * 16;
      off[f * 2]     = ex * 128 + (lk >> 2);
      off[f * 2 + 1] = ex * 128 + (lk >> 2) + 1;
    }
  } else {
    #pragma unroll
    for (int f = 0; f < 10; ++f) {
      int ex = lrow + ((f >= 5) ? 16 : 0);
      int ks = (f >= 5) ? (f - 5) : f;
      int hk = kw * 160 - 128 + ks * 32 + lk;
      off[f * 2]     = ex * 128 + (hk >> 2);
      off[f * 2 + 1] = ex * 128 + (hk >> 2) + 1;
    }
  }
  const int npoll = (kw == 0) ? 4 : 20;

  float c_state = 0.f;                         // carry for (b_ep, j)

  for (int t = 0; t < S_N; ++t) {
    // ---- wave 0: cached emb fragments (8x 16B) ----
    short8 eb[2][4];
    if (kw == 0) {
      #pragma unroll
      for (int f = 0; f < 2; ++f) {
        int ex = lrow + f * 16;
        const __hip_bfloat16* ep = emb + ((size_t)t * B_N + ex) * D_E + lk;
        #pragma unroll
        for (int ks = 0; ks < 4; ++ks)
          eb[f][ks] = *(const short8*)(ep + ks * 32);
      }
    }
    // ---- poll h fragments directly into registers ----
    u64 hv[20];
    if (t == 0) {
      #pragma unroll
      for (int id = 0; id < 20; ++id) hv[id] = 0ull;
    } else {
      const u64* src = (const u64*)hs + (size_t)(t - 1) * 4096;
      unsigned pend = (npoll == 4) ? 0xFu : 0xFFFFFu;
      while (pend) {
        #pragma unroll
        for (int id = 0; id < 20; ++id)
          if (id < npoll && (pend & (1u << id)))
            hv[id] = __hip_atomic_load(src + off[id], __ATOMIC_RELAXED,
                                       __HIP_MEMORY_SCOPE_AGENT);
        #pragma unroll
        for (int id = 0; id < 20; ++id)
          if (id < npoll && (pend & (1u << id)) && hv[id] != SENT64)
            pend &= ~(1u << id);
      }
    }

    // ---- MFMA: wave kw, all 64 rows x 32 cols over its K-slice 160 ----
    {
      f32x4 acc[4][2] = {};
      #pragma unroll
      for (int ks = 0; ks < 5; ++ks) {
        short8 b0, b1;
        if (kw == 0) {
          if (ks < 4) { b0 = eb[0][ks]; b1 = eb[1][ks]; }
          else        { b0 = frag2(hv[0], hv[1]); b1 = frag2(hv[2], hv[3]); }
        } else {
          b0 = frag2(hv[2 * ks], hv[2 * ks + 1]);
          b1 = frag2(hv[10 + 2 * ks], hv[11 + 2 * ks]);
        }
        #pragma unroll
        for (int mt = 0; mt < 4; ++mt) {
          acc[mt][0] = __builtin_amdgcn_mfma_f32_16x16x32_bf16(Afrag[mt * 5 + ks], b0, acc[mt][0], 0, 0, 0);
          acc[mt][1] = __builtin_amdgcn_mfma_f32_16x16x32_bf16(Afrag[mt * 5 + ks], b1, acc[mt][1], 0, 0, 0);
        }
      }
      #pragma unroll
      for (int mt = 0; mt < 4; ++mt)
        #pragma unroll
        for (int nt = 0; nt < 2; ++nt)
          #pragma unroll
          for (int r = 0; r < 4; ++r)
            gl4[kw][mt * 16 + (lane >> 4) * 4 + r][nt * 16 + (lane & 15)] = acc[mt][nt][r];
    }
    __syncthreads();                 // A: all waves' partials ready

    // ---- epilogue: thread <-> (b_ep, jj_ep); sum 4 K-partials ----
    {
      float cand_c[2], cand_h[2];
      #pragma unroll
      for (int k = 0; k < 2; ++k) {
        int base = k * 8 + jj_ep;
        float ig = gl4[0][base][b_ep] + gl4[1][base][b_ep]
                 + gl4[2][base][b_ep] + gl4[3][base][b_ep] + bias[base];
        float fg = gl4[0][16 + base][b_ep] + gl4[1][16 + base][b_ep]
                 + gl4[2][16 + base][b_ep] + gl4[3][16 + base][b_ep] + bias[16 + base];
        float gg = gl4[0][32 + base][b_ep] + gl4[1][32 + base][b_ep]
                 + gl4[2][32 + base][b_ep] + gl4[3][32 + base][b_ep] + bias[32 + base];
        float og = gl4[0][48 + base][b_ep] + gl4[1][48 + base][b_ep]
                 + gl4[2][48 + base][b_ep] + gl4[3][48 + base][b_ep] + bias[48 + base];
        ig = 1.f / (1.f + __expf(-ig));
        fg = 1.f / (1.f + __expf(-fg));
        og = 1.f / (1.f + __expf(-og));
        gg = ftanh(gg);
        float cn = fg * c_state + ig * gg;
        cand_c[k] = cn;
        cand_h[k] = og * ftanh(cn);
      }
      int sel = (par[t >> 5] >> (t & 31)) & 1;
      c_state  = sel ? cand_c[1] : cand_c[0];
      float hv2 = sel ? cand_h[1] : cand_h[0];
      __hip_bfloat16 hb = __float2bfloat16(hv2);
      hloc[jj_ep][b_ep] = *(const unsigned short*)&hb;
    }
    __syncthreads();                 // B: hloc complete; gl4 free for next step

    // ---- publish h(t) into hs[t]: fire-and-forget bypass stores ----
    if (tid < 64) {
      int b = tid >> 1, half = tid & 1;
      u64 v = (u64)hloc[half * 4 + 0][b]
            | ((u64)hloc[half * 4 + 1][b] << 16)
            | ((u64)hloc[half * 4 + 2][b] << 32)
            | ((u64)hloc[half * 4 + 3][b] << 48);
      u64* dst = (u64*)hs + (size_t)t * 4096 + b * 128 + wg * 2 + half;
      __hip_atomic_store(dst, v, __ATOMIC_RELAXED, __HIP_MEMORY_SCOPE_AGENT);
    }
    // no wait, no flag: consumers poll the data itself
  }
}

// ------------------------------------------------------------------
// logits GEMM: M=16384 (=S*B), N=10000, K=512, bf16 MFMA, +bias.
// Deterministic fused softmax-denominator: per-block per-row partial
// sum(exp(logit)) -> unique slot rowpart[row][tn] (NO atomics).
__launch_bounds__(256, 2)
__global__ void k_gemm(const __hip_bfloat16* __restrict__ hs,
                       const __hip_bfloat16* __restrict__ wout,
                       const float* __restrict__ b_out,
                       float* __restrict__ out,
                       float* __restrict__ rowpart)   // [16384][80]
{
  __shared__ __hip_bfloat16 Al[128][72];
  __shared__ __hip_bfloat16 Wt[128][72];
  __shared__ float sumLDS[2][128];         // [nq][row_local]
  const int tid = threadIdx.x;
  const int tn = blockIdx.x, tm = blockIdx.y;
  const int lane = tid & 63, wv = tid >> 6;
  const int mq = wv & 1, nq = wv >> 1;
  const int lrow = lane & 15, lk = (lane >> 4) * 8;
  f32x4 acc[4][4] = {};

  const int ar = tid >> 3, ac = (tid & 7) * 8;
  for (int k0 = 0; k0 < 512; k0 += 64) {
    __syncthreads();
    #pragma unroll
    for (int rr = 0; rr < 4; ++rr) {
      int r = ar + rr * 32;
      short8 av = *(const short8*)(hs + ((size_t)(tm * 128 + r)) * 512 + k0 + ac);
      *(short8*)&Al[r][ac] = av;
      int v = tn * 128 + r;
      short8 wvv = {};
      if (v < V_N) wvv = *(const short8*)(wout + (size_t)v * 512 + k0 + ac);
      *(short8*)&Wt[r][ac] = wvv;
    }
    __syncthreads();
    #pragma unroll
    for (int ks = 0; ks < 2; ++ks) {
      int kb = ks * 32 + lk;
      short8 af[4], bf[4];
      #pragma unroll
      for (int i = 0; i < 4; ++i) af[i] = *(const short8*)&Al[mq * 64 + i * 16 + lrow][kb];
      #pragma unroll
      for (int i = 0; i < 4; ++i) bf[i] = *(const short8*)&Wt[nq * 64 + i * 16 + lrow][kb];
      #pragma unroll
      for (int i = 0; i < 4; ++i)
        #pragma unroll
        for (int jx = 0; jx < 4; ++jx)
          acc[i][jx] = __builtin_amdgcn_mfma_f32_16x16x32_bf16(af[i], bf[jx], acc[i][jx], 0, 0, 0);
    }
  }
  const int rbase = tm * 128 + mq * 64 + (lane >> 4) * 4;
  const int cbase = tn * 128 + nq * 64 + (lane & 15);
  float esum[4][4];
  #pragma unroll
  for (int i = 0; i < 4; ++i)
    #pragma unroll
    for (int r = 0; r < 4; ++r) esum[i][r] = 0.f;

  #pragma unroll
  for (int i = 0; i < 4; ++i) {
    #pragma unroll
    for (int jx = 0; jx < 4; ++jx) {
      int col = cbase + jx * 16;
      if (col < V_N) {
        float bo = b_out[col];
        #pragma unroll
        for (int r = 0; r < 4; ++r) {
          int row = rbase + i * 16 + r;
          float lg = acc[i][jx][r] + bo;
          out[(size_t)row * V_N + col] = lg;
          esum[i][r] += __expf(lg);
        }
      }
    }
  }
  // reduce each (i,r) over the 16 lanes of the col group; write LDS partial
  #pragma unroll
  for (int i = 0; i < 4; ++i) {
    #pragma unroll
    for (int r = 0; r < 4; ++r) {
      float s = esum[i][r];
      s += __shfl_xor(s, 1); s += __shfl_xor(s, 2);
      s += __shfl_xor(s, 4); s += __shfl_xor(s, 8);
      if ((lane & 15) == 0)
        sumLDS[nq][mq * 64 + i * 16 + (lane >> 4) * 4 + r] = s;
    }
  }
  __syncthreads();
  if (tid < 128)   // one plain store per (row, tile): deterministic slot
    rowpart[(size_t)(tm * 128 + tid) * 80 + tn] = sumLDS[0][tid] + sumLDS[1][tid];
}

// ------------------------------------------------------------------
// fix-up: lse[r] = log(sum of 79 partials, fixed order); out[r][:] -= lse
__launch_bounds__(256)
__global__ void k_lsm_fix(float* __restrict__ out, const float* __restrict__ rowpart) {
  const int r = blockIdx.x;
  const float* rp = rowpart + (size_t)r * 80;
  float s = 0.f;
  for (int p = 0; p < 79; ++p) s += rp[p];   // same order in every thread/replay
  float lse = __logf(s);
  float4* q4 = (float4*)(out + (size_t)r * V_N);
  for (int i = threadIdx.x; i < V_N / 4; i += 256) {
    float4 v = q4[i];
    v.x -= lse; v.y -= lse; v.z -= lse; v.w -= lse;
    q4[i] = v;
  }
}

// ------------------------------------------------------------------
extern "C" void kernel_launch(void* const* d_in, const int* in_sizes, int n_in,
                              void* d_out, int out_size, void* d_ws, size_t ws_size,
                              hipStream_t stream) {
  const int*   x    = (const int*)d_in[0];
  const float* tab  = (const float*)d_in[1];
  const float* Wih  = (const float*)d_in[2];
  const float* Whh  = (const float*)d_in[3];
  const float* bih  = (const float*)d_in[4];
  const float* bhh  = (const float*)d_in[5];
  const float* Wout = (const float*)d_in[6];
  const float* bout = (const float*)d_in[7];
  float* out = (float*)d_out;

  char* ws = (char*)d_ws;
  float*           rowpart = (float*)(ws + OFF_RP);
  __hip_bfloat16*  emb     = (__hip_bfloat16*)(ws + OFF_EMB);
  __hip_bfloat16*  hsbuf   = (__hip_bfloat16*)(ws + OFF_HS);
  __hip_bfloat16*  wob     = (__hip_bfloat16*)(ws + OFF_WOUT);

  // re-poison hs to the write-once sentinel every launch (replay-safe)
  hipMemsetAsync(hsbuf, 0xFF, (size_t)S_N * B_N * H_N * 2, stream);
  k_prep_emb<<<(S_N * B_N * D_E) / 256, 256, 0, stream>>>(x, tab, emb);
  k_prep_wout<<<(V_N * H_N) / 256, 256, 0, stream>>>(Wout, wob);
  k_recurrence<<<64, 256, 0, stream>>>(x, Wih, Whh, bih, bhh, emb, hsbuf);
  k_gemm<<<dim3(79, 128), 256, 0, stream>>>(hsbuf, wob, bout, out, rowpart);
  k_lsm_fix<<<16384, 256, 0, stream>>>(out, rowpart);
}

// Round 9
// 3289.432 us; speedup vs baseline: 1.1959x; 1.1959x over previous
//
#include <hip/hip_runtime.h>
#include <hip/hip_bf16.h>

typedef __attribute__((ext_vector_type(8))) short short8;
typedef __attribute__((ext_vector_type(4))) float f32x4;
typedef unsigned long long u64;

#define V_N 10000
#define D_E 128
#define H_N 512
#define B_N 32
#define S_N 512

#define SENT64 0xFFFFFFFFFFFFFFFFull   // 4x bf16 NaN: unreachable for finite h

// ---- workspace layout (bytes) ----
#define OFF_RP    0                        // rowpart: 16384 rows x 80 slots f32 = 5,242,880
#define OFF_EMB   5242880                  // S*B*D bf16 = 4,194,304
#define OFF_HS    (OFF_EMB + 4194304)      // S*B*H bf16 = 16,777,216
#define OFF_WOUT  (OFF_HS + 16777216)      // V*H bf16 = 10,240,000

// ------------------------------------------------------------------
__device__ __forceinline__ float ftanh(float x) {
  float e = __expf(-2.f * fabsf(x));          // in (0,1], overflow-safe
  float r = (1.f - e) / (1.f + e);
  return __builtin_copysignf(r, x);
}

union U128 { f32x4 f; u64 q[2]; };

// ------------------------------------------------------------------
// prep: embedding gather -> bf16 [s][b][d]
__global__ void k_prep_emb(const int* __restrict__ x, const float* __restrict__ tab,
                           __hip_bfloat16* __restrict__ emb) {
  int i = blockIdx.x * 256 + threadIdx.x;         // over S*B*D = 2,097,152
  if (i >= S_N * B_N * D_E) return;
  int d  = i & (D_E - 1);
  int sb = i >> 7;
  int b  = sb & (B_N - 1);
  int s  = sb >> 5;
  int tok = x[b * S_N + s];
  emb[i] = __float2bfloat16(tab[tok * D_E + d]);
}

// prep: W_out -> bf16
__global__ void k_prep_wout(const float* __restrict__ w, __hip_bfloat16* __restrict__ o) {
  int i = blockIdx.x * 256 + threadIdx.x;
  if (i < V_N * H_N) o[i] = __float2bfloat16(w[i]);
}

// ------------------------------------------------------------------
// persistent recurrence: 64 WGs, WG w owns h-elements j = 8w..8w+7.
// A (weights) in registers; K=640 split across 4 waves; B staged in LDS.
// Readiness: wave 0 spins on 64 CANARY u64 (one per producer, its last data
// word) -> 64 requests/sweep instead of 4096. Then ONE coalesced sweep of
// 16-B bypass loads stages all of h(t-1); per-chunk sentinel check catches
// rare stragglers (canary visible before a sibling store).
__launch_bounds__(256, 1)
__global__ void k_recurrence(const int* __restrict__ x,
                             const float* __restrict__ W_ih, const float* __restrict__ W_hh,
                             const float* __restrict__ b_ih, const float* __restrict__ b_hh,
                             const __hip_bfloat16* __restrict__ emb,
                             __hip_bfloat16* __restrict__ hs)     // [512][32][512]
{
  __shared__ __hip_bfloat16 Bl[32][648];   // [example][k] = [emb_t ; h_prev]
  __shared__ float gl4t[4][32][66];        // [kw][col(example)][row(gate)] padded
  __shared__ float bias[64];
  __shared__ unsigned short hloc[8][32];   // [jj][b] bf16 bits of new h

  const int tid = threadIdx.x;
  const int wg  = blockIdx.x;              // 0..63
  const int lane = tid & 63, kw = tid >> 6;       // kw = wave = K-slice
  const int lrow = lane & 15, lk = (lane >> 4) * 8;
  const int b_ep = tid & 31, jj_ep = tid >> 5;    // epilogue mapping 32x8

  // ---- one-time: A-fragments (64 rows x K-slice 160) into registers ----
  short8 Afrag[20];                        // [mt*5+ks], 80 VGPRs
  #pragma unroll
  for (int mt = 0; mt < 4; ++mt) {
    #pragma unroll
    for (int ks = 0; ks < 5; ++ks) {
      int lr = mt * 16 + lrow;             // local gate row 0..63
      int q = lr >> 4, kc = (lr >> 3) & 1, jj = lr & 7;
      int grow = kc * 2048 + q * 512 + wg * 8 + jj;
      int c0 = kw * 160 + ks * 32 + lk;
      short8 a;
      #pragma unroll
      for (int e = 0; e < 8; ++e) {
        int c = c0 + e;
        float v = (c < 128) ? W_ih[(size_t)grow * 128 + c]
                            : W_hh[(size_t)grow * 512 + (c - 128)];
        __hip_bfloat16 hb = __float2bfloat16(v);
        a[e] = *(const short*)&hb;
      }
      Afrag[mt * 5 + ks] = a;
    }
  }
  if (tid < 64) {
    int lr = tid;
    int q = lr >> 4, kc = (lr >> 3) & 1, jj = lr & 7;
    int grow = kc * 2048 + q * 512 + wg * 8 + jj;
    bias[lr] = b_ih[grow] + b_hh[grow];
  }

  // ---- preload token parity bits into registers (b_ep's row of x) ----
  unsigned par[16];
  #pragma unroll
  for (int w = 0; w < 16; ++w) {
    unsigned p = 0;
    for (int bb = 0; bb < 32; ++bb)
      p |= (unsigned)(x[b_ep * S_N + w * 32 + bb] & 1) << bb;
    par[w] = p;
  }

  // per-thread bulk region: 16 u64 = 128 B of hs[t] (coalesced across threads)
  const int myb  = tid >> 3;               // example row (i/8)
  const int hh0  = (tid & 7) * 16;         // first u64 within row
  float c_state = 0.f;                         // carry for (b_ep, j)
  const u64* e64base = (const u64*)emb;

  for (int t = 0; t < S_N; ++t) {
    // ---- stage emb_t (plain cached loads, 8B) — overlaps the spin ----
    const u64* e64 = e64base + (size_t)t * 1024;   // 32*128 bf16 = 1024 u64
    for (int i = tid; i < 1024; i += 256) {
      int b = i >> 5, dd = i & 31;
      *(u64*)&Bl[b][dd * 4] = e64[i];
    }

    if (t == 0) {
      for (int i = tid; i < 4096; i += 256) {
        int b = i >> 7, hh = i & 127;
        *(u64*)&Bl[b][128 + hh * 4] = 0ull;
      }
      __syncthreads();
    } else {
      // ---- canary spin: wave 0, lane l watches producer l's last word ----
      if (tid < 64) {
        const u64* can = (const u64*)hs + (size_t)(t - 1) * 4096 + 3968 + tid * 2 + 1;
        u64 v;
        do {
          v = __hip_atomic_load(can, __ATOMIC_RELAXED, __HIP_MEMORY_SCOPE_AGENT);
        } while (!__all((int)(v != SENT64)));
      }
      __syncthreads();
      // ---- single coalesced bulk sweep: 8 x 16-B bypass loads/thread ----
      const char* src = (const char*)hs + (size_t)(t - 1) * 32768 + tid * 128;
      U128 buf[8];
      unsigned pend = 0xFFu;
      while (pend) {
        #pragma unroll
        for (int c = 0; c < 8; ++c)
          if (pend & (1u << c))
            asm volatile("global_load_dwordx4 %0, %1, off sc0 sc1"
                         : "=v"(buf[c].f) : "v"(src + c * 16) : "memory");
        asm volatile("s_waitcnt vmcnt(0)" ::: "memory");
        __builtin_amdgcn_sched_barrier(0);
        #pragma unroll
        for (int c = 0; c < 8; ++c)
          if ((pend & (1u << c)) && buf[c].q[0] != SENT64 && buf[c].q[1] != SENT64) {
            *(f32x4*)&Bl[myb][128 + (hh0 + c * 2) * 4] = buf[c].f;
            pend &= ~(1u << c);
          }
      }
      __syncthreads();
    }

    // ---- MFMA: wave kw computes all 64 rows x 32 cols over K-slice 160 ----
    {
      f32x4 acc[4][2] = {};
      #pragma unroll
      for (int ks = 0; ks < 5; ++ks) {
        int cb = (kw * 160 + ks * 32 + lk) * 2;    // byte offset in a row
        short8 b0 = *(const short8*)((const char*)&Bl[0][0] + lrow * 1296 + cb);
        short8 b1 = *(const short8*)((const char*)&Bl[0][0] + (16 + lrow) * 1296 + cb);
        #pragma unroll
        for (int mt = 0; mt < 4; ++mt) {
          acc[mt][0] = __builtin_amdgcn_mfma_f32_16x16x32_bf16(Afrag[mt * 5 + ks], b0, acc[mt][0], 0, 0, 0);
          acc[mt][1] = __builtin_amdgcn_mfma_f32_16x16x32_bf16(Afrag[mt * 5 + ks], b1, acc[mt][1], 0, 0, 0);
        }
      }
      #pragma unroll
      for (int mt = 0; mt < 4; ++mt)
        #pragma unroll
        for (int nt = 0; nt < 2; ++nt)
          *(f32x4*)&gl4t[kw][nt * 16 + (lane & 15)][mt * 16 + (lane >> 4) * 4] = acc[mt][nt];
    }
    __syncthreads();                 // all waves' partials in gl4t

    // ---- epilogue: thread <-> (b_ep, jj_ep); sum 4 K-partials ----
    {
      float cand_c[2], cand_h[2];
      #pragma unroll
      for (int k = 0; k < 2; ++k) {
        int base = k * 8 + jj_ep;
        float ig = gl4t[0][b_ep][base] + gl4t[1][b_ep][base]
                 + gl4t[2][b_ep][base] + gl4t[3][b_ep][base] + bias[base];
        float fg = gl4t[0][b_ep][16 + base] + gl4t[1][b_ep][16 + base]
                 + gl4t[2][b_ep][16 + base] + gl4t[3][b_ep][16 + base] + bias[16 + base];
        float gg = gl4t[0][b_ep][32 + base] + gl4t[1][b_ep][32 + base]
                 + gl4t[2][b_ep][32 + base] + gl4t[3][b_ep][32 + base] + bias[32 + base];
        float og = gl4t[0][b_ep][48 + base] + gl4t[1][b_ep][48 + base]
                 + gl4t[2][b_ep][48 + base] + gl4t[3][b_ep][48 + base] + bias[48 + base];
        ig = 1.f / (1.f + __expf(-ig));
        fg = 1.f / (1.f + __expf(-fg));
        og = 1.f / (1.f + __expf(-og));
        gg = ftanh(gg);
        float cn = fg * c_state + ig * gg;
        cand_c[k] = cn;
        cand_h[k] = og * ftanh(cn);
      }
      int sel = (par[t >> 5] >> (t & 31)) & 1;
      c_state  = sel ? cand_c[1] : cand_c[0];
      float hv = sel ? cand_h[1] : cand_h[0];
      __hip_bfloat16 hb = __float2bfloat16(hv);
      hloc[jj_ep][b_ep] = *(const unsigned short*)&hb;
    }
    __syncthreads();                 // hloc complete; gl4t free for next step

    // ---- publish h(t) into hs[t]: fire-and-forget bypass stores ----
    if (tid < 64) {
      int b = tid >> 1, half = tid & 1;
      u64 v = (u64)hloc[half * 4 + 0][b]
            | ((u64)hloc[half * 4 + 1][b] << 16)
            | ((u64)hloc[half * 4 + 2][b] << 32)
            | ((u64)hloc[half * 4 + 3][b] << 48);
      u64* dst = (u64*)hs + (size_t)t * 4096 + b * 128 + wg * 2 + half;
      __hip_atomic_store(dst, v, __ATOMIC_RELAXED, __HIP_MEMORY_SCOPE_AGENT);
    }
    // no wait, no flag: canary (b=31,half=1 word) + sentinel check handle it
  }
}

// ------------------------------------------------------------------
// logits GEMM: M=16384 (=S*B), N=10000, K=512, bf16 MFMA, +bias.
// Deterministic fused softmax-denominator: per-block per-row partial
// sum(exp(logit)) -> unique slot rowpart[row][tn] (NO atomics).
__launch_bounds__(256, 2)
__global__ void k_gemm(const __hip_bfloat16* __restrict__ hs,
                       const __hip_bfloat16* __restrict__ wout,
                       const float* __restrict__ b_out,
                       float* __restrict__ out,
                       float* __restrict__ rowpart)   // [16384][80]
{
  __shared__ __hip_bfloat16 Al[128][72];
  __shared__ __hip_bfloat16 Wt[128][72];
  __shared__ float sumLDS[2][128];         // [nq][row_local]
  const int tid = threadIdx.x;
  const int tn = blockIdx.x, tm = blockIdx.y;
  const int lane = tid & 63, wv = tid >> 6;
  const int mq = wv & 1, nq = wv >> 1;
  const int lrow = lane & 15, lk = (lane >> 4) * 8;
  f32x4 acc[4][4] = {};

  const int ar = tid >> 3, ac = (tid & 7) * 8;
  for (int k0 = 0; k0 < 512; k0 += 64) {
    __syncthreads();
    #pragma unroll
    for (int rr = 0; rr < 4; ++rr) {
      int r = ar + rr * 32;
      short8 av = *(const short8*)(hs + ((size_t)(tm * 128 + r)) * 512 + k0 + ac);
      *(short8*)&Al[r][ac] = av;
      int v = tn * 128 + r;
      short8 wvv = {};
      if (v < V_N) wvv = *(const short8*)(wout + (size_t)v * 512 + k0 + ac);
      *(short8*)&Wt[r][ac] = wvv;
    }
    __syncthreads();
    #pragma unroll
    for (int ks = 0; ks < 2; ++ks) {
      int kb = ks * 32 + lk;
      short8 af[4], bf[4];
      #pragma unroll
      for (int i = 0; i < 4; ++i) af[i] = *(const short8*)&Al[mq * 64 + i * 16 + lrow][kb];
      #pragma unroll
      for (int i = 0; i < 4; ++i) bf[i] = *(const short8*)&Wt[nq * 64 + i * 16 + lrow][kb];
      #pragma unroll
      for (int i = 0; i < 4; ++i)
        #pragma unroll
        for (int jx = 0; jx < 4; ++jx)
          acc[i][jx] = __builtin_amdgcn_mfma_f32_16x16x32_bf16(af[i], bf[jx], acc[i][jx], 0, 0, 0);
    }
  }
  const int rbase = tm * 128 + mq * 64 + (lane >> 4) * 4;
  const int cbase = tn * 128 + nq * 64 + (lane & 15);
  float esum[4][4];
  #pragma unroll
  for (int i = 0; i < 4; ++i)
    #pragma unroll
    for (int r = 0; r < 4; ++r) esum[i][r] = 0.f;

  #pragma unroll
  for (int i = 0; i < 4; ++i) {
    #pragma unroll
    for (int jx = 0; jx < 4; ++jx) {
      int col = cbase + jx * 16;
      if (col < V_N) {
        float bo = b_out[col];
        #pragma unroll
        for (int r = 0; r < 4; ++r) {
          int row = rbase + i * 16 + r;
          float lg = acc[i][jx][r] + bo;
          out[(size_t)row * V_N + col] = lg;
          esum[i][r] += __expf(lg);
        }
      }
    }
  }
  // reduce each (i,r) over the 16 lanes of the col group; write LDS partial
  #pragma unroll
  for (int i = 0; i < 4; ++i) {
    #pragma unroll
    for (int r = 0; r < 4; ++r) {
      float s = esum[i][r];
      s += __shfl_xor(s, 1); s += __shfl_xor(s, 2);
      s += __shfl_xor(s, 4); s += __shfl_xor(s, 8);
      if ((lane & 15) == 0)
        sumLDS[nq][mq * 64 + i * 16 + (lane >> 4) * 4 + r] = s;
    }
  }
  __syncthreads();
  if (tid < 128)   // one plain store per (row, tile): deterministic slot
    rowpart[(size_t)(tm * 128 + tid) * 80 + tn] = sumLDS[0][tid] + sumLDS[1][tid];
}

// ------------------------------------------------------------------
// fix-up: lse[r] = log(sum of 79 partials, fixed order); out[r][:] -= lse
__launch_bounds__(256)
__global__ void k_lsm_fix(float* __restrict__ out, const float* __restrict__ rowpart) {
  const int r = blockIdx.x;
  const float* rp = rowpart + (size_t)r * 80;
  float s = 0.f;
  for (int p = 0; p < 79; ++p) s += rp[p];   // same order in every thread/replay
  float lse = __logf(s);
  float4* q4 = (float4*)(out + (size_t)r * V_N);
  for (int i = threadIdx.x; i < V_N / 4; i += 256) {
    float4 v = q4[i];
    v.x -= lse; v.y -= lse; v.z -= lse; v.w -= lse;
    q4[i] = v;
  }
}

// ------------------------------------------------------------------
extern "C" void kernel_launch(void* const* d_in, const int* in_sizes, int n_in,
                              void* d_out, int out_size, void* d_ws, size_t ws_size,
                              hipStream_t stream) {
  const int*   x    = (const int*)d_in[0];
  const float* tab  = (const float*)d_in[1];
  const float* Wih  = (const float*)d_in[2];
  const float* Whh  = (const float*)d_in[3];
  const float* bih  = (const float*)d_in[4];
  const float* bhh  = (const float*)d_in[5];
  const float* Wout = (const float*)d_in[6];
  const float* bout = (const float*)d_in[7];
  float* out = (float*)d_out;

  char* ws = (char*)d_ws;
  float*           rowpart = (float*)(ws + OFF_RP);
  __hip_bfloat16*  emb     = (__hip_bfloat16*)(ws + OFF_EMB);
  __hip_bfloat16*  hsbuf   = (__hip_bfloat16*)(ws + OFF_HS);
  __hip_bfloat16*  wob     = (__hip_bfloat16*)(ws + OFF_WOUT);

  // re-poison hs to the write-once sentinel every launch (replay-safe)
  hipMemsetAsync(hsbuf, 0xFF, (size_t)S_N * B_N * H_N * 2, stream);
  k_prep_emb<<<(S_N * B_N * D_E) / 256, 256, 0, stream>>>(x, tab, emb);
  k_prep_wout<<<(V_N * H_N) / 256, 256, 0, stream>>>(Wout, wob);
  k_recurrence<<<64, 256, 0, stream>>>(x, Wih, Whh, bih, bhh, emb, hsbuf);
  k_gemm<<<dim3(79, 128), 256, 0, stream>>>(hsbuf, wob, bout, out, rowpart);
  k_lsm_fix<<<16384, 256, 0, stream>>>(out, rowpart);
}

// Round 10
// 2556.127 us; speedup vs baseline: 1.5390x; 1.2869x over previous
//
#include <hip/hip_runtime.h>
#include <hip/hip_bf16.h>

typedef __attribute__((ext_vector_type(8))) short short8;
typedef __attribute__((ext_vector_type(4))) float f32x4;
typedef unsigned long long u64;

#define V_N 10000
#define D_E 128
#define H_N 512
#define B_N 32
#define S_N 512

#define SENT64 0xFFFFFFFFFFFFFFFFull   // 4x bf16 NaN: unreachable for finite h

// ---- workspace layout (bytes) ----
#define OFF_RP    0                        // rowpart: 16384 rows x 80 slots f32 = 5,242,880
#define OFF_EMB   5242880                  // S*B*D bf16 = 4,194,304
#define OFF_HS    (OFF_EMB + 4194304)      // S*B*H bf16 = 16,777,216
#define OFF_WOUT  (OFF_HS + 16777216)      // V*H bf16 = 10,240,000

// ------------------------------------------------------------------
__device__ __forceinline__ float ftanh(float x) {
  float e = __expf(-2.f * fabsf(x));          // in (0,1], overflow-safe
  float r = (1.f - e) / (1.f + e);
  return __builtin_copysignf(r, x);
}

union U128 { f32x4 f; u64 q[2]; };

// ------------------------------------------------------------------
// prep: embedding gather -> bf16 [s][b][d]
__global__ void k_prep_emb(const int* __restrict__ x, const float* __restrict__ tab,
                           __hip_bfloat16* __restrict__ emb) {
  int i = blockIdx.x * 256 + threadIdx.x;         // over S*B*D = 2,097,152
  if (i >= S_N * B_N * D_E) return;
  int d  = i & (D_E - 1);
  int sb = i >> 7;
  int b  = sb & (B_N - 1);
  int s  = sb >> 5;
  int tok = x[b * S_N + s];
  emb[i] = __float2bfloat16(tab[tok * D_E + d]);
}

// prep: W_out -> bf16
__global__ void k_prep_wout(const float* __restrict__ w, __hip_bfloat16* __restrict__ o) {
  int i = blockIdx.x * 256 + threadIdx.x;
  if (i < V_N * H_N) o[i] = __float2bfloat16(w[i]);
}

// ------------------------------------------------------------------
// persistent recurrence: 64 WGs, WG w owns h-elements j = 8w..8w+7.
// A (weights) in registers; K=640 split across 4 waves; B staged in LDS.
// Cross-WG exchange: write-once sentinel slots in hs[t]; consumers poll the
// data itself with 16-B bypass loads (masked retry). Linear chunk<->thread
// mapping: coalesced global sweep AND conflict-free consecutive-b128 LDS
// commit. Publish is fire-and-forget.
__launch_bounds__(256, 1)
__global__ void k_recurrence(const int* __restrict__ x,
                             const float* __restrict__ W_ih, const float* __restrict__ W_hh,
                             const float* __restrict__ b_ih, const float* __restrict__ b_hh,
                             const __hip_bfloat16* __restrict__ emb,
                             __hip_bfloat16* __restrict__ hs)     // [512][32][512]
{
  __shared__ __align__(16) __hip_bfloat16 Bl[32][648];  // [example][emb128 ; h512]
  __shared__ float gl4[4][64][33];         // per-wave partial gates (r7 layout)
  __shared__ float bias[64];
  __shared__ unsigned short hloc[8][32];   // [jj][b] bf16 bits of new h

  const int tid = threadIdx.x;
  const int wg  = blockIdx.x;              // 0..63
  const int lane = tid & 63, kw = tid >> 6;       // kw = wave = K-slice
  const int lrow = lane & 15, lk = (lane >> 4) * 8;
  const int b_ep = tid & 31, jj_ep = tid >> 5;    // epilogue mapping 32x8

  // ---- one-time: A-fragments (64 rows x K-slice 160) into registers ----
  short8 Afrag[20];                        // [mt*5+ks], 80 VGPRs
  #pragma unroll
  for (int mt = 0; mt < 4; ++mt) {
    #pragma unroll
    for (int ks = 0; ks < 5; ++ks) {
      int lr = mt * 16 + lrow;             // local gate row 0..63
      int q = lr >> 4, kc = (lr >> 3) & 1, jj = lr & 7;
      int grow = kc * 2048 + q * 512 + wg * 8 + jj;
      int c0 = kw * 160 + ks * 32 + lk;
      short8 a;
      #pragma unroll
      for (int e = 0; e < 8; ++e) {
        int c = c0 + e;
        float v = (c < 128) ? W_ih[(size_t)grow * 128 + c]
                            : W_hh[(size_t)grow * 512 + (c - 128)];
        __hip_bfloat16 hb = __float2bfloat16(v);
        a[e] = *(const short*)&hb;
      }
      Afrag[mt * 5 + ks] = a;
    }
  }
  if (tid < 64) {
    int lr = tid;
    int q = lr >> 4, kc = (lr >> 3) & 1, jj = lr & 7;
    int grow = kc * 2048 + q * 512 + wg * 8 + jj;
    bias[lr] = b_ih[grow] + b_hh[grow];
  }

  // ---- preload token parity bits into registers (b_ep's row of x) ----
  unsigned par[16];
  #pragma unroll
  for (int w = 0; w < 16; ++w) {
    unsigned p = 0;
    for (int bb = 0; bb < 32; ++bb)
      p |= (unsigned)(x[b_ep * S_N + w * 32 + bb] & 1) << bb;
    par[w] = p;
  }

  float c_state = 0.f;                         // carry for (b_ep, j)

  for (int t = 0; t < S_N; ++t) {
    // ---- stage emb_t: 2 x 16B cached loads/thread (coalesced) ----
    {
      const f32x4* e16 = (const f32x4*)(emb + (size_t)t * B_N * D_E);  // 512 chunks
      #pragma unroll
      for (int c = 0; c < 2; ++c) {
        int ci = c * 256 + tid;            // 0..511
        int ex = ci >> 4, col = ci & 15;
        *(f32x4*)((char*)&Bl[0][0] + ex * 1296 + col * 16) = e16[ci];
      }
    }
    // ---- stage h_prev: masked 16-B sentinel poll, linear mapping ----
    if (t == 0) {
      for (int i = tid; i < 4096; i += 256) {
        int b = i >> 7, hh = i & 127;
        *(u64*)&Bl[b][128 + hh * 4] = 0ull;
      }
    } else {
      const char* srcb = (const char*)hs + (size_t)(t - 1) * 32768;
      U128 buf[8];
      unsigned pend = 0xFFu;
      while (pend) {
        #pragma unroll
        for (int c = 0; c < 8; ++c)
          if (pend & (1u << c))
            asm volatile("global_load_dwordx4 %0, %1, off sc0 sc1"
                         : "=v"(buf[c].f) : "v"(srcb + (c * 4096 + tid * 16)) : "memory");
        asm volatile("s_waitcnt vmcnt(0)" ::: "memory");
        __builtin_amdgcn_sched_barrier(0);
        #pragma unroll
        for (int c = 0; c < 8; ++c)
          if ((pend & (1u << c)) && buf[c].q[0] != SENT64 && buf[c].q[1] != SENT64) {
            int ci = c * 256 + tid;        // chunk 0..2047
            *(f32x4*)((char*)&Bl[0][0] + (ci >> 6) * 1296 + 256 + (ci & 63) * 16) = buf[c].f;
            pend &= ~(1u << c);
          }
      }
    }
    __syncthreads();

    // ---- MFMA: wave kw computes all 64 rows x 32 cols over K-slice 160 ----
    {
      f32x4 acc[4][2] = {};
      #pragma unroll
      for (int ks = 0; ks < 5; ++ks) {
        int cb = (kw * 160 + ks * 32 + lk) * 2;    // byte offset in a row
        short8 b0 = *(const short8*)((const char*)&Bl[0][0] + lrow * 1296 + cb);
        short8 b1 = *(const short8*)((const char*)&Bl[0][0] + (16 + lrow) * 1296 + cb);
        #pragma unroll
        for (int mt = 0; mt < 4; ++mt) {
          acc[mt][0] = __builtin_amdgcn_mfma_f32_16x16x32_bf16(Afrag[mt * 5 + ks], b0, acc[mt][0], 0, 0, 0);
          acc[mt][1] = __builtin_amdgcn_mfma_f32_16x16x32_bf16(Afrag[mt * 5 + ks], b1, acc[mt][1], 0, 0, 0);
        }
      }
      #pragma unroll
      for (int mt = 0; mt < 4; ++mt)
        #pragma unroll
        for (int nt = 0; nt < 2; ++nt)
          #pragma unroll
          for (int r = 0; r < 4; ++r)
            gl4[kw][mt * 16 + (lane >> 4) * 4 + r][nt * 16 + (lane & 15)] = acc[mt][nt][r];
    }
    __syncthreads();                 // A: all waves' partials ready

    // ---- epilogue: thread <-> (b_ep, jj_ep); sum 4 K-partials ----
    {
      float cand_c[2], cand_h[2];
      #pragma unroll
      for (int k = 0; k < 2; ++k) {
        int base = k * 8 + jj_ep;
        float ig = gl4[0][base][b_ep] + gl4[1][base][b_ep]
                 + gl4[2][base][b_ep] + gl4[3][base][b_ep] + bias[base];
        float fg = gl4[0][16 + base][b_ep] + gl4[1][16 + base][b_ep]
                 + gl4[2][16 + base][b_ep] + gl4[3][16 + base][b_ep] + bias[16 + base];
        float gg = gl4[0][32 + base][b_ep] + gl4[1][32 + base][b_ep]
                 + gl4[2][32 + base][b_ep] + gl4[3][32 + base][b_ep] + bias[32 + base];
        float og = gl4[0][48 + base][b_ep] + gl4[1][48 + base][b_ep]
                 + gl4[2][48 + base][b_ep] + gl4[3][48 + base][b_ep] + bias[48 + base];
        ig = 1.f / (1.f + __expf(-ig));
        fg = 1.f / (1.f + __expf(-fg));
        og = 1.f / (1.f + __expf(-og));
        gg = ftanh(gg);
        float cn = fg * c_state + ig * gg;
        cand_c[k] = cn;
        cand_h[k] = og * ftanh(cn);
      }
      int sel = (par[t >> 5] >> (t & 31)) & 1;
      c_state  = sel ? cand_c[1] : cand_c[0];
      float hv = sel ? cand_h[1] : cand_h[0];
      __hip_bfloat16 hb = __float2bfloat16(hv);
      hloc[jj_ep][b_ep] = *(const unsigned short*)&hb;
    }
    __syncthreads();                 // B: hloc complete; Bl/gl4 free next step

    // ---- publish h(t) into hs[t]: fire-and-forget bypass stores ----
    if (tid < 64) {
      int b = tid >> 1, half = tid & 1;
      u64 v = (u64)hloc[half * 4 + 0][b]
            | ((u64)hloc[half * 4 + 1][b] << 16)
            | ((u64)hloc[half * 4 + 2][b] << 32)
            | ((u64)hloc[half * 4 + 3][b] << 48);
      u64* dst = (u64*)hs + (size_t)t * 4096 + b * 128 + wg * 2 + half;
      __hip_atomic_store(dst, v, __ATOMIC_RELAXED, __HIP_MEMORY_SCOPE_AGENT);
    }
    // no wait, no flag: consumers poll the data itself
  }
}

// ------------------------------------------------------------------
// logits GEMM: M=16384 (=S*B), N=10000, K=512, bf16 MFMA, +bias.
// Deterministic fused softmax-denominator: per-block per-row partial
// sum(exp(logit)) -> unique slot rowpart[row][tn] (NO atomics).
__launch_bounds__(256, 2)
__global__ void k_gemm(const __hip_bfloat16* __restrict__ hs,
                       const __hip_bfloat16* __restrict__ wout,
                       const float* __restrict__ b_out,
                       float* __restrict__ out,
                       float* __restrict__ rowpart)   // [16384][80]
{
  __shared__ __hip_bfloat16 Al[128][72];
  __shared__ __hip_bfloat16 Wt[128][72];
  __shared__ float sumLDS[2][128];         // [nq][row_local]
  const int tid = threadIdx.x;
  const int tn = blockIdx.x, tm = blockIdx.y;
  const int lane = tid & 63, wv = tid >> 6;
  const int mq = wv & 1, nq = wv >> 1;
  const int lrow = lane & 15, lk = (lane >> 4) * 8;
  f32x4 acc[4][4] = {};

  const int ar = tid >> 3, ac = (tid & 7) * 8;
  for (int k0 = 0; k0 < 512; k0 += 64) {
    __syncthreads();
    #pragma unroll
    for (int rr = 0; rr < 4; ++rr) {
      int r = ar + rr * 32;
      short8 av = *(const short8*)(hs + ((size_t)(tm * 128 + r)) * 512 + k0 + ac);
      *(short8*)&Al[r][ac] = av;
      int v = tn * 128 + r;
      short8 wvv = {};
      if (v < V_N) wvv = *(const short8*)(wout + (size_t)v * 512 + k0 + ac);
      *(short8*)&Wt[r][ac] = wvv;
    }
    __syncthreads();
    #pragma unroll
    for (int ks = 0; ks < 2; ++ks) {
      int kb = ks * 32 + lk;
      short8 af[4], bf[4];
      #pragma unroll
      for (int i = 0; i < 4; ++i) af[i] = *(const short8*)&Al[mq * 64 + i * 16 + lrow][kb];
      #pragma unroll
      for (int i = 0; i < 4; ++i) bf[i] = *(const short8*)&Wt[nq * 64 + i * 16 + lrow][kb];
      #pragma unroll
      for (int i = 0; i < 4; ++i)
        #pragma unroll
        for (int jx = 0; jx < 4; ++jx)
          acc[i][jx] = __builtin_amdgcn_mfma_f32_16x16x32_bf16(af[i], bf[jx], acc[i][jx], 0, 0, 0);
    }
  }
  const int rbase = tm * 128 + mq * 64 + (lane >> 4) * 4;
  const int cbase = tn * 128 + nq * 64 + (lane & 15);
  float esum[4][4];
  #pragma unroll
  for (int i = 0; i < 4; ++i)
    #pragma unroll
    for (int r = 0; r < 4; ++r) esum[i][r] = 0.f;

  #pragma unroll
  for (int i = 0; i < 4; ++i) {
    #pragma unroll
    for (int jx = 0; jx < 4; ++jx) {
      int col = cbase + jx * 16;
      if (col < V_N) {
        float bo = b_out[col];
        #pragma unroll
        for (int r = 0; r < 4; ++r) {
          int row = rbase + i * 16 + r;
          float lg = acc[i][jx][r] + bo;
          out[(size_t)row * V_N + col] = lg;
          esum[i][r] += __expf(lg);
        }
      }
    }
  }
  // reduce each (i,r) over the 16 lanes of the col group; write LDS partial
  #pragma unroll
  for (int i = 0; i < 4; ++i) {
    #pragma unroll
    for (int r = 0; r < 4; ++r) {
      float s = esum[i][r];
      s += __shfl_xor(s, 1); s += __shfl_xor(s, 2);
      s += __shfl_xor(s, 4); s += __shfl_xor(s, 8);
      if ((lane & 15) == 0)
        sumLDS[nq][mq * 64 + i * 16 + (lane >> 4) * 4 + r] = s;
    }
  }
  __syncthreads();
  if (tid < 128)   // one plain store per (row, tile): deterministic slot
    rowpart[(size_t)(tm * 128 + tid) * 80 + tn] = sumLDS[0][tid] + sumLDS[1][tid];
}

// ------------------------------------------------------------------
// fix-up: lse[r] = log(sum of 79 partials, fixed order); out[r][:] -= lse
__launch_bounds__(256)
__global__ void k_lsm_fix(float* __restrict__ out, const float* __restrict__ rowpart) {
  const int r = blockIdx.x;
  const float* rp = rowpart + (size_t)r * 80;
  float s = 0.f;
  for (int p = 0; p < 79; ++p) s += rp[p];   // same order in every thread/replay
  float lse = __logf(s);
  float4* q4 = (float4*)(out + (size_t)r * V_N);
  for (int i = threadIdx.x; i < V_N / 4; i += 256) {
    float4 v = q4[i];
    v.x -= lse; v.y -= lse; v.z -= lse; v.w -= lse;
    q4[i] = v;
  }
}

// ------------------------------------------------------------------
extern "C" void kernel_launch(void* const* d_in, const int* in_sizes, int n_in,
                              void* d_out, int out_size, void* d_ws, size_t ws_size,
                              hipStream_t stream) {
  const int*   x    = (const int*)d_in[0];
  const float* tab  = (const float*)d_in[1];
  const float* Wih  = (const float*)d_in[2];
  const float* Whh  = (const float*)d_in[3];
  const float* bih  = (const float*)d_in[4];
  const float* bhh  = (const float*)d_in[5];
  const float* Wout = (const float*)d_in[6];
  const float* bout = (const float*)d_in[7];
  float* out = (float*)d_out;

  char* ws = (char*)d_ws;
  float*           rowpart = (float*)(ws + OFF_RP);
  __hip_bfloat16*  emb     = (__hip_bfloat16*)(ws + OFF_EMB);
  __hip_bfloat16*  hsbuf   = (__hip_bfloat16*)(ws + OFF_HS);
  __hip_bfloat16*  wob     = (__hip_bfloat16*)(ws + OFF_WOUT);

  // re-poison hs to the write-once sentinel every launch (replay-safe)
  hipMemsetAsync(hsbuf, 0xFF, (size_t)S_N * B_N * H_N * 2, stream);
  k_prep_emb<<<(S_N * B_N * D_E) / 256, 256, 0, stream>>>(x, tab, emb);
  k_prep_wout<<<(V_N * H_N) / 256, 256, 0, stream>>>(Wout, wob);
  k_recurrence<<<64, 256, 0, stream>>>(x, Wih, Whh, bih, bhh, emb, hsbuf);
  k_gemm<<<dim3(79, 128), 256, 0, stream>>>(hsbuf, wob, bout, out, rowpart);
  k_lsm_fix<<<16384, 256, 0, stream>>>(out, rowpart);
}